// Round 1
// baseline (1198.377 us; speedup 1.0000x reference)
//
#include <hip/hip_runtime.h>
#include <math.h>

// Problem constants (fixed by the reference)
#define B_    64
#define LOOKB 32
#define NS    256
#define DM    512
#define DK    128
#define DV    128

__device__ __forceinline__ float sigmoidf_(float x) {
    return 1.0f / (1.0f + expf(-x));
}

// max_lag arrives as a 1-element array; Python int -> int32, but be robust to
// a float32 encoding too (bits of 16.0f are >= 2^23, so this disambiguates).
__device__ __forceinline__ float load_maxlag(const void* p) {
    int vi = *(const int*)p;
    if (vi >= 0 && vi < (1 << 23)) return (float)vi;
    return *(const float*)p;
}

__device__ __forceinline__ void lag_params(const float* __restrict__ lags,
                                           float maxlag, int s,
                                           int& lf, int& lc, float& alpha) {
    float lag = sigmoidf_(lags[s]) * maxlag;
    float lf_f = fminf(fmaxf(floorf(lag), 0.0f), (float)(LOOKB - 1));
    float lc_f = fminf(fmaxf(ceilf(lag), 0.0f), (float)(LOOKB - 1));
    lf = (int)lf_f;
    lc = (int)lc_f;
    alpha = lag - lf_f;
}

// ---------------------------------------------------------------------------
// K0: m[b,d] = sum_k q[b,k] * W_k[k,d],  q[b,k] = sum_d' query[b,d'] * W_q[k,d']
// grid: B_ blocks x 256 threads
// ---------------------------------------------------------------------------
__global__ void k_prep(const float* __restrict__ query,
                       const float* __restrict__ Wq,
                       const float* __restrict__ Wk,
                       float* __restrict__ ws_m) {
    __shared__ float qe[DM];
    __shared__ float qv[DK];
    const int b = blockIdx.x;
    const int tid = threadIdx.x;

    qe[tid]       = query[b * DM + tid];
    qe[tid + 256] = query[b * DM + tid + 256];
    __syncthreads();

    if (tid < DK) {
        const float4* wr = (const float4*)(Wq + (size_t)tid * DM);
        const float4* qr = (const float4*)qe;
        float acc = 0.f;
#pragma unroll 8
        for (int i = 0; i < DM / 4; ++i) {
            float4 w = wr[i], q4 = qr[i];
            acc += w.x * q4.x + w.y * q4.y + w.z * q4.z + w.w * q4.w;
        }
        qv[tid] = acc;
    }
    __syncthreads();

    // coalesced across d: thread t handles d = t, t+256
    for (int d = tid; d < DM; d += 256) {
        float acc = 0.f;
#pragma unroll 8
        for (int k = 0; k < DK; ++k)
            acc += qv[k] * Wk[(size_t)k * DM + d];
        ws_m[b * DM + d] = acc;
    }
}

// ---------------------------------------------------------------------------
// KA: scores[b,s] = gate[s] * (m[b] . interp_emb[b,s]) / sqrt(DK)
// One wave per (b,s); 4 waves/block share b. grid: B_*64 blocks x 256 thr.
// Each lane loads 8 floats (2x float4) of each of the two gathered rows.
// ---------------------------------------------------------------------------
__global__ void k_scores(const float* __restrict__ embs,
                         const float* __restrict__ lags,
                         const float* __restrict__ gates,
                         const void*  __restrict__ maxlag_p,
                         const float* __restrict__ ws_m,
                         float* __restrict__ ws_scores) {
    const int tid  = threadIdx.x;
    const int b     = blockIdx.x >> 6;
    const int sbase = (blockIdx.x & 63) << 2;
    const int wave  = tid >> 6;
    const int lane  = tid & 63;
    const int s     = sbase + wave;

    const float maxlag = load_maxlag(maxlag_p);
    int lf, lc; float alpha;
    lag_params(lags, maxlag, s, lf, lc, alpha);
    const float gate = sigmoidf_(gates[s]);

    const size_t off = (size_t)lane * 8;
    const float* mrow = ws_m + (size_t)b * DM + off;
    float4 m0 = *(const float4*)(mrow);
    float4 m1 = *(const float4*)(mrow + 4);

    const size_t bf = (((size_t)b * LOOKB + lf) * NS + s) * (size_t)DM + off;
    const size_t bc = (((size_t)b * LOOKB + lc) * NS + s) * (size_t)DM + off;
    float4 f0 = *(const float4*)(embs + bf);
    float4 f1 = *(const float4*)(embs + bf + 4);
    float4 c0 = *(const float4*)(embs + bc);
    float4 c1 = *(const float4*)(embs + bc + 4);

    float acc = m0.x * (f0.x + alpha * (c0.x - f0.x))
              + m0.y * (f0.y + alpha * (c0.y - f0.y))
              + m0.z * (f0.z + alpha * (c0.z - f0.z))
              + m0.w * (f0.w + alpha * (c0.w - f0.w))
              + m1.x * (f1.x + alpha * (c1.x - f1.x))
              + m1.y * (f1.y + alpha * (c1.y - f1.y))
              + m1.z * (f1.z + alpha * (c1.z - f1.z))
              + m1.w * (f1.w + alpha * (c1.w - f1.w));

#pragma unroll
    for (int off2 = 32; off2; off2 >>= 1)
        acc += __shfl_xor(acc, off2, 64);

    if (lane == 0)
        ws_scores[b * NS + s] = gate * acc * 0.0883883476483184405f; // 1/sqrt(128)
}

// ---------------------------------------------------------------------------
// KB: softmax over the 256 stocks of each batch row. grid: B_ x 256 thr.
// ---------------------------------------------------------------------------
__global__ void k_softmax(const float* __restrict__ ws_scores,
                          float* __restrict__ ws_attn) {
    __shared__ float rmax[4];
    __shared__ float rsum[4];
    const int b = blockIdx.x, tid = threadIdx.x;
    const int wave = tid >> 6, lane = tid & 63;

    float v = ws_scores[b * NS + tid];
    float m = v;
#pragma unroll
    for (int off = 32; off; off >>= 1)
        m = fmaxf(m, __shfl_xor(m, off, 64));
    if (lane == 0) rmax[wave] = m;
    __syncthreads();
    const float mx = fmaxf(fmaxf(rmax[0], rmax[1]), fmaxf(rmax[2], rmax[3]));

    float e = expf(v - mx);
    float ssum = e;
#pragma unroll
    for (int off = 32; off; off >>= 1)
        ssum += __shfl_xor(ssum, off, 64);
    if (lane == 0) rsum[wave] = ssum;
    __syncthreads();
    const float tot = rsum[0] + rsum[1] + rsum[2] + rsum[3];

    ws_attn[b * NS + tid] = e / tot;
}

// ---------------------------------------------------------------------------
// KC: partial ctx_d[b,d] = sum_{s in chunk} attn[b,s] * interp_emb[b,s,d]
// grid: B_*8 blocks x 256 thr. Each block handles 32 stocks, thread owns
// d0 = tid*2 (float2, coalesced). Partials -> ws_part (no atomics).
// ---------------------------------------------------------------------------
__global__ void k_ctx(const float* __restrict__ embs,
                      const float* __restrict__ lags,
                      const void*  __restrict__ maxlag_p,
                      const float* __restrict__ ws_attn,
                      float* __restrict__ ws_part) {
    const int b     = blockIdx.x >> 3;
    const int chunk = blockIdx.x & 7;
    const int tid   = threadIdx.x;
    const int d0    = tid * 2;
    const float maxlag = load_maxlag(maxlag_p);

    float ax = 0.f, ay = 0.f;
    const int s0 = chunk * 32;
#pragma unroll 4
    for (int i = 0; i < 32; ++i) {
        const int s = s0 + i;
        int lf, lc; float alpha;
        lag_params(lags, maxlag, s, lf, lc, alpha);
        const float w = ws_attn[b * NS + s];

        const size_t bf = (((size_t)b * LOOKB + lf) * NS + s) * (size_t)DM + d0;
        const size_t bc = (((size_t)b * LOOKB + lc) * NS + s) * (size_t)DM + d0;
        float2 ef = *(const float2*)(embs + bf);
        float2 ec = *(const float2*)(embs + bc);
        ax += w * (ef.x + alpha * (ec.x - ef.x));
        ay += w * (ef.y + alpha * (ec.y - ef.y));
    }
    float2 outv; outv.x = ax; outv.y = ay;
    *(float2*)(ws_part + ((size_t)(b * 8 + chunk)) * DM + d0) = outv;
}

// ---------------------------------------------------------------------------
// KD: ctx_d[b] = sum of 8 partials; out[b,v] = W_v[v,:] . ctx_d[b]
// grid: B_ blocks x 128 threads (one per v)
// ---------------------------------------------------------------------------
__global__ void k_out(const float* __restrict__ ws_part,
                      const float* __restrict__ Wv,
                      float* __restrict__ out) {
    __shared__ float ctx[DM];
    const int b = blockIdx.x, tid = threadIdx.x;

    for (int d = tid; d < DM; d += 128) {
        float a = 0.f;
#pragma unroll
        for (int c = 0; c < 8; ++c)
            a += ws_part[((size_t)(b * 8 + c)) * DM + d];
        ctx[d] = a;
    }
    __syncthreads();

    const float4* wr = (const float4*)(Wv + (size_t)tid * DM);
    const float4* cr = (const float4*)ctx;
    float acc = 0.f;
#pragma unroll 8
    for (int i = 0; i < DM / 4; ++i) {
        float4 w = wr[i], c = cr[i];
        acc += w.x * c.x + w.y * c.y + w.z * c.z + w.w * c.w;
    }
    out[b * DV + tid] = acc;
}

// ---------------------------------------------------------------------------
extern "C" void kernel_launch(void* const* d_in, const int* in_sizes, int n_in,
                              void* d_out, int out_size, void* d_ws, size_t ws_size,
                              hipStream_t stream) {
    const float* query = (const float*)d_in[0];   // (B, DM)
    const float* embs  = (const float*)d_in[1];   // (B, LOOKB, NS, DM)
    const float* Wq    = (const float*)d_in[2];   // (DK, DM)
    const float* Wk    = (const float*)d_in[3];   // (DK, DM)
    const float* Wv    = (const float*)d_in[4];   // (DV, DM)
    const float* lags  = (const float*)d_in[5];   // (NS,)
    const float* gates = (const float*)d_in[6];   // (NS,)
    const void*  maxlag_p = d_in[7];              // scalar

    float* out = (float*)d_out;                   // (B, DV) fp32

    // Workspace layout (floats): m | scores | attn | partials
    float* ws        = (float*)d_ws;
    float* ws_m      = ws;                        // B*DM      = 32768
    float* ws_scores = ws + 32768;                // B*NS      = 16384
    float* ws_attn   = ws + 49152;                // B*NS      = 16384
    float* ws_part   = ws + 65536;                // B*8*DM    = 262144
    (void)in_sizes; (void)n_in; (void)out_size; (void)ws_size;

    k_prep<<<B_, 256, 0, stream>>>(query, Wq, Wk, ws_m);
    k_scores<<<B_ * 64, 256, 0, stream>>>(embs, lags, gates, maxlag_p, ws_m, ws_scores);
    k_softmax<<<B_, 256, 0, stream>>>(ws_scores, ws_attn);
    k_ctx<<<B_ * 8, 256, 0, stream>>>(embs, lags, maxlag_p, ws_attn, ws_part);
    k_out<<<B_, 128, 0, stream>>>(ws_part, Wv, out);
}